// Round 4
// baseline (575.069 us; speedup 1.0000x reference)
//
#include <hip/hip_runtime.h>
#include <stdint.h>

typedef short bf16x8 __attribute__((ext_vector_type(8)));
typedef short s16x4 __attribute__((ext_vector_type(4)));
typedef float f32x4 __attribute__((ext_vector_type(4)));
typedef unsigned int u32;

#define EPS_A 1e-8f
#define THR_A 1e-6f
#define NN 8192

static __device__ __forceinline__ short f2bf(float f) {
  u32 u = __float_as_uint(f);
  u = u + 0x7FFFu + ((u >> 16) & 1u);   // RNE, no NaN inputs here
  return (short)(u >> 16);
}
static __device__ __forceinline__ float bf2f(short s) {
  return __uint_as_float(((u32)(unsigned short)s) << 16);
}

// ---- P1: single pass over M: transpose-cast -> Mt bf16 [i][j], colsum, colmax
__global__ __launch_bounds__(256) void k_prep_mt(
    const float* __restrict__ M, short* __restrict__ Mt,
    float* __restrict__ colsum, u32* __restrict__ colmax)
{
  __shared__ __align__(16) short tile[256 * 66];  // [i_local][j_local], stride 66
  const int t = threadIdx.x;
  const int i0 = blockIdx.x * 256;
  const int j0 = blockIdx.y * 64;
  const int i = i0 + t;
  float s = 0.f, mx = 0.f;
  #pragma unroll 4
  for (int jj = 0; jj < 64; ++jj) {
    float v = M[(size_t)(j0 + jj) * NN + i];    // coalesced: t -> i
    s += v;
    mx = fmaxf(mx, v);
    tile[t * 66 + jj] = f2bf(v);
  }
  atomicAdd(&colsum[i], s);
  atomicMax(&colmax[i], __float_as_uint(mx));   // M >= 0, uint order == float order
  __syncthreads();
  // write out rows i (128B each, 8 threads x 16B), coalesced
  #pragma unroll
  for (int p = 0; p < 8; ++p) {
    const int r = p * 32 + (t >> 3);
    const int c = t & 7;
    const u32* src = (const u32*)((const char*)tile + r * 132 + c * 16); // 4B aligned
    int4 w = make_int4(src[0], src[1], src[2], src[3]);
    *(int4*)((char*)Mt + (((size_t)(i0 + r) * NN + j0) * 2 + c * 16)) = w;
  }
}

// ---- cast node_features fp32 -> bf16 into Acat1 cols 512:768 (ld 768)
__global__ __launch_bounds__(256) void k_cast_nf(const float* __restrict__ nf,
                                                 short* __restrict__ acat) {
  const int idx = blockIdx.x * 256 + threadIdx.x;   // one float4 each; 524288 total
  const float4 v = ((const float4*)nf)[idx];
  const int i = idx >> 6;         // 64 float4 per 256-wide row
  const int c = (idx & 63) * 4;
  s16x4 o;
  o.x = f2bf(v.x); o.y = f2bf(v.y); o.z = f2bf(v.z); o.w = f2bf(v.w);
  *(s16x4*)&acat[(size_t)i * 768 + 512 + c] = o;
}

// ---- generic small transpose-cast: out[c*ldo + r] = bf16(in[r*C + c])
__global__ __launch_bounds__(256) void k_tcast(const float* __restrict__ in, int R, int C,
                                               short* __restrict__ out, int ldo) {
  const int idx = blockIdx.x * 256 + threadIdx.x;
  if (idx >= R * C) return;
  const int r = idx / C, c = idx % C;
  out[(size_t)c * ldo + r] = f2bf(in[idx]);
}

// ---- uniform GEMM body: C[M,N] = A[M,K] @ B[N,K]^T, bf16 in, fp32 acc
// 128x128 tile, BK=32, reg-staged LDS (global->VGPR->ds_write_b128)
// EPI 0: += bias0[m], bf16 out        (T-GEMMs, C = T^T)
// EPI 1: agg epilogue (colsum/colmax/Tfall), bf16 out
// EPI 2: += bias0[n]+bias1[n], fp32 out
template <int EPI>
__device__ __forceinline__ void gemm_body(
    const short* __restrict__ A, const short* __restrict__ B, int K, int ldA, int ldB,
    void* __restrict__ Cout, int ldC,
    const float* __restrict__ bias0, const float* __restrict__ bias1,
    const float* __restrict__ colsum, const u32* __restrict__ colmax,
    const short* __restrict__ Tfall)
{
  __shared__ __align__(16) short As[128 * 32];
  __shared__ __align__(16) short Bs[128 * 32];
  const int t = threadIdx.x;
  const int m0 = blockIdx.y * 128, n0 = blockIdx.x * 128;
  const int wid = t >> 6, l = t & 63;
  const int wr = wid >> 1, wc = wid & 1;      // 2x2 waves, 64x64 each
  const int lr = l & 15, lk = l >> 4;

  f32x4 acc[4][4] = {};

  const int sr = t >> 2;                      // staging row 0..63 (and +64)
  const int sc = (t & 3) * 8;                 // short col 0/8/16/24
  const short* gA0 = A + (size_t)(m0 + sr) * ldA + sc;
  const short* gA1 = A + (size_t)(m0 + 64 + sr) * ldA + sc;
  const short* gB0 = B + (size_t)(n0 + sr) * ldB + sc;
  const short* gB1 = B + (size_t)(n0 + 64 + sr) * ldB + sc;

  for (int k0 = 0; k0 < K; k0 += 32) {
    const int4 a0 = *(const int4*)(gA0 + k0);
    const int4 a1 = *(const int4*)(gA1 + k0);
    const int4 b0 = *(const int4*)(gB0 + k0);
    const int4 b1 = *(const int4*)(gB1 + k0);
    __syncthreads();                          // protect previous iteration's reads
    *(int4*)&As[sr * 32 + sc] = a0;
    *(int4*)&As[(64 + sr) * 32 + sc] = a1;
    *(int4*)&Bs[sr * 32 + sc] = b0;
    *(int4*)&Bs[(64 + sr) * 32 + sc] = b1;
    __syncthreads();

    bf16x8 av[4], bv[4];
    #pragma unroll
    for (int mi = 0; mi < 4; ++mi)
      av[mi] = *(const bf16x8*)&As[(wr * 64 + mi * 16 + lr) * 32 + lk * 8];
    #pragma unroll
    for (int ni = 0; ni < 4; ++ni)
      bv[ni] = *(const bf16x8*)&Bs[(wc * 64 + ni * 16 + lr) * 32 + lk * 8];
    #pragma unroll
    for (int mi = 0; mi < 4; ++mi)
      #pragma unroll
      for (int ni = 0; ni < 4; ++ni)
        acc[mi][ni] = __builtin_amdgcn_mfma_f32_16x16x32_bf16(av[mi], bv[ni], acc[mi][ni], 0, 0, 0);
  }

  #pragma unroll
  for (int mi = 0; mi < 4; ++mi) {
    #pragma unroll
    for (int ni = 0; ni < 4; ++ni) {
      #pragma unroll
      for (int r = 0; r < 4; ++r) {
        const int m = m0 + wr * 64 + mi * 16 + lk * 4 + r;  // C: col=lane&15, row=(lane>>4)*4+r
        const int n = n0 + wc * 64 + ni * 16 + lr;
        float v = acc[mi][ni][r];
        if (EPI == 0) {
          v += bias0[m];
          ((short*)Cout)[(size_t)m * ldC + n] = f2bf(v);
        } else if (EPI == 1) {
          const float cs = colsum[m];
          const float rc = 1.f / (cs + EPS_A);
          const float wsum = cs * rc;
          const bool he = __uint_as_float(colmax[m]) * rc > THR_A;
          v = he ? (v * rc) / (wsum + EPS_A) : bf2f(Tfall[(size_t)n * NN + m]);
          ((short*)Cout)[(size_t)m * ldC + n] = f2bf(v);
        } else {
          v += bias0[n] + bias1[n];
          ((float*)Cout)[(size_t)m * ldC + n] = v;
        }
      }
    }
  }
}

__global__ __launch_bounds__(256) void k_gemm_bias(
    const short* __restrict__ A, const short* __restrict__ B, int K, int ldA, int ldB,
    void* __restrict__ C, int ldC, const float* __restrict__ bias0) {
  gemm_body<0>(A, B, K, ldA, ldB, C, ldC, bias0, nullptr, nullptr, nullptr, nullptr);
}
__global__ __launch_bounds__(256) void k_gemm_agg(
    const short* __restrict__ A, const short* __restrict__ B, int K, int ldA, int ldB,
    void* __restrict__ C, int ldC, const float* __restrict__ colsum,
    const u32* __restrict__ colmax, const short* __restrict__ Tfall) {
  gemm_body<1>(A, B, K, ldA, ldB, C, ldC, nullptr, nullptr, colsum, colmax, Tfall);
}
__global__ __launch_bounds__(256) void k_gemm_out(
    const short* __restrict__ A, const short* __restrict__ B, int K, int ldA, int ldB,
    void* __restrict__ C, int ldC, const float* __restrict__ bias0,
    const float* __restrict__ bias1) {
  gemm_body<2>(A, B, K, ldA, ldB, C, ldC, bias0, bias1, nullptr, nullptr, nullptr);
}

// ---- row LayerNorm + ReLU, fp32 in.
// MODE 0: bf16 out, ld-strided (inter-layer activation)
// MODE 1: fp32 out (final d_out — reference output dtype is float32!)
template <int MODE>
__device__ __forceinline__ void ln_relu_body(
    const float* __restrict__ X, int W,
    const float* __restrict__ g, const float* __restrict__ be,
    void* __restrict__ out, int ldo)
{
  const int row = blockIdx.x;
  const int t = threadIdx.x;
  const float* x = X + (size_t)row * W;
  float v0 = x[t], v1 = 0.f;
  float s = v0, ss = v0 * v0;
  if (W == 512) { v1 = x[t + 256]; s += v1; ss += v1 * v1; }
  #pragma unroll
  for (int off = 32; off; off >>= 1) {
    s += __shfl_down(s, off);
    ss += __shfl_down(ss, off);
  }
  __shared__ float red[8];
  const int wid = t >> 6;
  if ((t & 63) == 0) { red[wid] = s; red[4 + wid] = ss; }
  __syncthreads();
  s = red[0] + red[1] + red[2] + red[3];
  ss = red[4] + red[5] + red[6] + red[7];
  const float mu = s / W;
  const float var = ss / W - mu * mu;
  const float sc = rsqrtf(var + 1e-5f);
  float y = fmaxf((v0 - mu) * sc * g[t] + be[t], 0.f);
  if (MODE == 0) ((short*)out)[(size_t)row * ldo + t] = f2bf(y);
  else           ((float*)out)[(size_t)row * ldo + t] = y;
  if (W == 512) {
    float y1 = fmaxf((v1 - mu) * sc * g[t + 256] + be[t + 256], 0.f);
    if (MODE == 0) ((short*)out)[(size_t)row * ldo + t + 256] = f2bf(y1);
    else           ((float*)out)[(size_t)row * ldo + t + 256] = y1;
  }
}

__global__ __launch_bounds__(256) void k_ln_relu_bf16(
    const float* __restrict__ X, int W, const float* __restrict__ g,
    const float* __restrict__ be, short* __restrict__ out, int ldo) {
  ln_relu_body<0>(X, W, g, be, out, ldo);
}
__global__ __launch_bounds__(256) void k_ln_relu_f32(
    const float* __restrict__ X, int W, const float* __restrict__ g,
    const float* __restrict__ be, float* __restrict__ out, int ldo) {
  ln_relu_body<1>(X, W, g, be, out, ldo);
}

extern "C" void kernel_launch(void* const* d_in, const int* in_sizes, int n_in,
                              void* d_out, int out_size, void* d_ws, size_t ws_size,
                              hipStream_t stream) {
  const float* nf      = (const float*)d_in[0];
  const float* Mob     = (const float*)d_in[1];
  const float* W_in1   = (const float*)d_in[2];
  const float* b_in1   = (const float*)d_in[3];
  const float* W_out1  = (const float*)d_in[4];
  const float* b_out1  = (const float*)d_in[5];
  const float* W_self1 = (const float*)d_in[6];
  const float* b_self1 = (const float*)d_in[7];
  const float* g1      = (const float*)d_in[8];
  const float* be1     = (const float*)d_in[9];
  const float* W_in2   = (const float*)d_in[10];
  const float* b_in2   = (const float*)d_in[11];
  const float* W_out2  = (const float*)d_in[12];
  const float* b_out2  = (const float*)d_in[13];
  const float* W_self2 = (const float*)d_in[14];
  const float* b_self2 = (const float*)d_in[15];
  const float* g2      = (const float*)d_in[16];
  const float* be2     = (const float*)d_in[17];

  char* ws = (char*)d_ws;
  float* colsum = (float*)(ws);                       // 8192 f32
  u32*   colmax = (u32*)(ws + 32768);                 // 8192 u32
  short* Mt     = (short*)(ws + 65536);               // [8192][8192] bf16 (unnormalized W^T)
  short* Acat1  = (short*)(ws + 134283264);           // [8192][768]: [agg1(512) | nf(256)]
  short* T1t    = (short*)(ws + 146866176);           // [512][8192]
  float* C2     = (float*)(ws + 155254784);           // [8192][512] f32 (reused [8192][256])
  short* Acat2  = (short*)(ws + 172032000);           // [8192][768]: [agg2(256) | h1(512)]
  short* T2t    = (short*)(ws + 184614912);           // [256][8192]
  short* Bcat1  = (short*)(ws + 188809216);           // [512][768]: [Wout1^T | Wself1^T]
  short* Bcat2  = (short*)(ws + 189595648);           // [256][768]: [Wout2^T | Wself2^T]
  short* Win1t  = (short*)(ws + 189988864);           // [512][256]
  short* Win2t  = (short*)(ws + 190251008);           // [256][512]

  hipMemsetAsync(ws, 0, 65536, stream);  // zero colsum + colmax every call

  k_prep_mt<<<dim3(32, 128), 256, 0, stream>>>(Mob, Mt, colsum, colmax);
  k_cast_nf<<<2048, 256, 0, stream>>>(nf, Acat1);
  k_tcast<<<512, 256, 0, stream>>>(W_in1, 256, 512, Win1t, 256);
  k_tcast<<<1024, 256, 0, stream>>>(W_out1, 512, 512, Bcat1, 768);
  k_tcast<<<512, 256, 0, stream>>>(W_self1, 256, 512, Bcat1 + 512, 768);
  k_tcast<<<512, 256, 0, stream>>>(W_in2, 512, 256, Win2t, 512);
  k_tcast<<<256, 256, 0, stream>>>(W_out2, 256, 256, Bcat2, 768);
  k_tcast<<<512, 256, 0, stream>>>(W_self2, 512, 256, Bcat2 + 256, 768);

  // layer 1
  k_gemm_bias<<<dim3(64, 4), 256, 0, stream>>>(Win1t, Acat1 + 512, 256, 256, 768,
                                               T1t, NN, b_in1);
  k_gemm_agg<<<dim3(4, 64), 256, 0, stream>>>(Mt, T1t, NN, NN, NN,
                                              Acat1, 768, colsum, colmax, T1t);
  k_gemm_out<<<dim3(4, 64), 256, 0, stream>>>(Acat1, Bcat1, 768, 768, 768,
                                              C2, 512, b_out1, b_self1);
  k_ln_relu_bf16<<<8192, 256, 0, stream>>>(C2, 512, g1, be1, Acat2 + 256, 768);

  // layer 2 (same W^T = Mt, colsum, colmax)
  k_gemm_bias<<<dim3(64, 2), 256, 0, stream>>>(Win2t, Acat2 + 256, 512, 512, 768,
                                               T2t, NN, b_in2);
  k_gemm_agg<<<dim3(2, 64), 256, 0, stream>>>(Mt, T2t, NN, NN, NN,
                                              Acat2, 768, colsum, colmax, T2t);
  k_gemm_out<<<dim3(2, 64), 256, 0, stream>>>(Acat2, Bcat2, 768, 768, 768,
                                              C2, 256, b_out2, b_self2);
  k_ln_relu_f32<<<8192, 256, 0, stream>>>(C2, 256, g2, be2, (float*)d_out, 256);
}